// Round 5
// baseline (901.953 us; speedup 1.0000x reference)
//
#include <hip/hip_runtime.h>

#define T_TOTAL 65536
#define SEQ 128
#define DMODEL 512
#define DHEAD 64
#define NTYPES 10000
#define ROWS 8192
#define NOUT_PAD 10240  // 40*256

typedef float floatx4 __attribute__((ext_vector_type(4)));
typedef short shortx8 __attribute__((ext_vector_type(8)));

#define GLOAD_LDS(gp, lp) __builtin_amdgcn_global_load_lds( \
    (const __attribute__((address_space(1))) void*)(gp),    \
    (__attribute__((address_space(3))) void*)(lp), 16, 0, 0)

#define MFMA_BF16 __builtin_amdgcn_mfma_f32_16x16x32_bf16

__device__ __forceinline__ unsigned short f2bf(float f) {
  union { float f; unsigned u; } v; v.f = f;
  unsigned u = v.u + 0x7fffu + ((v.u >> 16) & 1u);
  return (unsigned short)(u >> 16);
}

__device__ __forceinline__ void phase_barrier() {
  __builtin_amdgcn_sched_barrier(0);
  __builtin_amdgcn_s_barrier();
  __builtin_amdgcn_sched_barrier(0);
}

// ------- prep: weight converts (grid-stride) + segment boundary table ------
__global__ __launch_bounds__(256) void prep_kernel(
    const float* __restrict__ Wqkv, const float* __restrict__ Wo,
    const float* __restrict__ W1, const float* __restrict__ W2,
    const float* __restrict__ Wout,
    unsigned short* __restrict__ wqkv_b, unsigned short* __restrict__ wo_b,
    unsigned short* __restrict__ w1_b, unsigned short* __restrict__ w2_b,
    unsigned short* __restrict__ wout_b,
    const int* __restrict__ seg_ids, int* __restrict__ starts) {
  long gid = (long)blockIdx.x * 256 + threadIdx.x;
  // segment boundaries: starts[s] = first index t with seg_ids[t] >= s
  if (gid < T_TOTAL) {
    int cur = seg_ids[gid];
    int prev = (gid == 0) ? -1 : seg_ids[gid - 1];
    for (int s = prev + 1; s <= cur; ++s) starts[s] = (int)gid;
    if (gid == T_TOTAL - 1)
      for (int s = cur + 1; s <= ROWS; ++s) starts[s] = T_TOTAL;
  }
  // weight converts, float4 granularity
  const long Q0 = 1572864L / 4;           // Wqkv
  const long Q1 = Q0 + 524288L / 4;       // Wo
  const long Q2 = Q1 + 1048576L / 4;      // W1
  const long Q3 = Q2 + 1048576L / 4;      // W2
  const long Q4 = Q3 + 5242880L / 4;      // Wout (padded dst)
  const long stride = 2048L * 256;
  for (long q = gid; q < Q4; q += stride) {
    const float* src; unsigned short* dst; long i; bool guard = false;
    if (q < Q0)      { src = Wqkv; dst = wqkv_b; i = q; }
    else if (q < Q1) { src = Wo;   dst = wo_b;   i = q - Q0; }
    else if (q < Q2) { src = W1;   dst = w1_b;   i = q - Q1; }
    else if (q < Q3) { src = W2;   dst = w2_b;   i = q - Q2; }
    else             { src = Wout; dst = wout_b; i = q - Q3; guard = true; }
    long e = i * 4;
    float4 v = make_float4(0.f, 0.f, 0.f, 0.f);
    if (!guard || e < 5120000L) v = *(const float4*)(src + e);
    ushort4 o;
    o.x = f2bf(v.x); o.y = f2bf(v.y); o.z = f2bf(v.z); o.w = f2bf(v.w);
    *(ushort4*)(dst + e) = o;
  }
}

// ------- segment-mean embedding + positional encoding (table-driven) -------
__global__ __launch_bounds__(128) void seg_mean_kernel(
    const int* __restrict__ item_ids, const int* __restrict__ starts,
    const float* __restrict__ emb, float* __restrict__ x_f,
    unsigned short* __restrict__ x_b) {
  int s = blockIdx.x;  // segment id = b*SEQ + l
  int start = starts[s], end = starts[s + 1];
  int c = threadIdx.x << 2;
  float4 acc = make_float4(0.f, 0.f, 0.f, 0.f);
  for (int j = start; j < end; ++j) {
    const float* e = emb + (long)item_ids[j] * DMODEL + c;
    float4 v = *(const float4*)e;
    acc.x += v.x; acc.y += v.y; acc.z += v.z; acc.w += v.w;
  }
  int cnt = end - start;
  float inv = cnt > 0 ? 1.0f / (float)cnt : 0.0f;
  float mv[4] = {acc.x * inv, acc.y * inv, acc.z * inv, acc.w * inv};
  int l = s & (SEQ - 1);
  const float klog = 0.017988946039015984f;  // ln(10000)/512
  long base = (long)s * DMODEL + c;
#pragma unroll
  for (int t = 0; t < 4; ++t) {
    int col = c + t;
    float den = expf(-(float)(col & ~1) * klog);
    float ang = (float)l * den;
    float pe = (col & 1) ? cosf(ang) : sinf(ang);
    float val = mv[t] + pe;
    x_f[base + t] = val;
    x_b[base + t] = f2bf(val);
  }
}

// ---------------- 128x128 bf16 MFMA GEMM (proven m97 structure) ------------
__global__ __launch_bounds__(256) void gemm_bt_kernel(
    const unsigned short* __restrict__ A,   // [M,K] bf16 row-major
    const unsigned short* __restrict__ B,   // [Npad,K] bf16 row-major
    const float* __restrict__ bias,         // [Nreal] or nullptr
    float* __restrict__ Cf,                 // [M,ldC] f32 or nullptr
    unsigned short* __restrict__ Cb,        // [M,ldC] bf16 or nullptr
    int K, int Nreal, int ldC, int relu) {
  __shared__ unsigned short As[128 * 32];
  __shared__ unsigned short Bs[128 * 32];
  const int tid = threadIdx.x;
  const int lane = tid & 63;
  const int wave = tid >> 6;
  const int wm = (wave >> 1) << 6;
  const int wn = (wave & 1) << 6;
  const int l16 = lane & 15;
  const int quad = lane >> 4;
  const long rowA0 = (long)blockIdx.x * 128;
  const long rowB0 = (long)blockIdx.y * 128;

  floatx4 acc[4][4] = {};

  const int rowOff = tid >> 2;        // 0..63
  const int kOff = (tid & 3) << 3;    // 0,8,16,24 (elements)
  const unsigned short* gA = A + (rowA0 + rowOff) * (long)K + kOff;
  const unsigned short* gB = B + (rowB0 + rowOff) * (long)K + kOff;
  unsigned short* lA = As + tid * 8;  // byte offset tid*16
  unsigned short* lB = Bs + tid * 8;

  for (int k0 = 0; k0 < K; k0 += 32) {
    __syncthreads();
    GLOAD_LDS(gA + k0, lA);
    GLOAD_LDS(gA + 64 * (long)K + k0, lA + 2048);
    GLOAD_LDS(gB + k0, lB);
    GLOAD_LDS(gB + 64 * (long)K + k0, lB + 2048);
    __syncthreads();
    shortx8 af[4], bfr[4];
#pragma unroll
    for (int i = 0; i < 4; ++i)
      af[i] = *(const shortx8*)(As + (wm + i * 16 + l16) * 32 + quad * 8);
#pragma unroll
    for (int j = 0; j < 4; ++j)
      bfr[j] = *(const shortx8*)(Bs + (wn + j * 16 + l16) * 32 + quad * 8);
#pragma unroll
    for (int i = 0; i < 4; ++i)
#pragma unroll
      for (int j = 0; j < 4; ++j)
        acc[i][j] = MFMA_BF16(af[i], bfr[j], acc[i][j], 0, 0, 0);
  }

#pragma unroll
  for (int i = 0; i < 4; ++i) {
    int row = (int)rowA0 + wm + i * 16 + quad * 4;
#pragma unroll
    for (int j = 0; j < 4; ++j) {
      int col = (int)rowB0 + wn + j * 16 + l16;
      if (col < Nreal) {
        float bv = bias ? bias[col] : 0.0f;
#pragma unroll
        for (int r = 0; r < 4; ++r) {
          float v = acc[i][j][r] + bv;
          if (relu) v = fmaxf(v, 0.0f);
          long off = (long)(row + r) * ldC + col;
          if (Cf) Cf[off] = v;
          if (Cb) Cb[off] = f2bf(v);
        }
      }
    }
  }
}

// ------- fused GEMM(512-col) + residual add + LayerNorm --------------------
// Tile 64 rows x 512 cols (full model row per block), grid = 128 blocks,
// 512 threads = 8 waves (2 row-halves x 4 col-quarters, wave tile 32x128).
// LDS rows are 32 elems (64 B) -> conflict-free fragment reads.
// Epilogue: e = acc + bias + x_f; row stats via l16-shfl + LDS cross-wave
// reduce; writes x_f (f32) and x_b (bf16). Safe aliasing: each thread reads
// only the x_f elements it later writes; rows are block-exclusive.
__global__ __launch_bounds__(512) void gemm_ln_kernel(
    const unsigned short* __restrict__ A,   // [8192,K] bf16
    const unsigned short* __restrict__ W,   // [512,K] bf16
    const float* __restrict__ bias,         // [512]
    const float* __restrict__ gamma, const float* __restrict__ beta,
    float* __restrict__ x_f,                // residual in/out [8192,512]
    unsigned short* __restrict__ x_b,       // bf16 out
    int K) {
  __shared__ unsigned short As[64 * 32];    // 4 KB
  __shared__ unsigned short Bs[512 * 32];   // 32 KB
  __shared__ float redS[64][4];
  __shared__ float redQ[64][4];
  __shared__ float meanr[64], rstdr[64];
  const int tid = threadIdx.x;
  const int lane = tid & 63;
  const int wave = tid >> 6;
  const int wr = wave >> 2;        // 0..1 row half (32 rows each)
  const int wc = wave & 3;         // 0..3 col quarter (128 cols each)
  const int l16 = lane & 15;
  const int quad = lane >> 4;
  const long row0 = (long)blockIdx.x * 64;

  floatx4 acc[2][8] = {};

  const unsigned short* gA = A + (row0 + (tid >> 2)) * (long)K + ((tid & 3) << 3);
  const unsigned short* gW = W + (long)(tid >> 2) * K + ((tid & 3) << 3);
  const long rstepW = 128 * (long)K;
  unsigned short* lA = As + tid * 8;        // used by tid<256 only
  unsigned short* lB = Bs + tid * 8;

  for (int k0 = 0; k0 < K; k0 += 32) {
    __syncthreads();
    if (tid < 256) GLOAD_LDS(gA + k0, lA);   // wave-uniform predicate
#pragma unroll
    for (int is = 0; is < 4; ++is)
      GLOAD_LDS(gW + is * rstepW + k0, lB + is * 4096);
    __syncthreads();
    shortx8 af[2], bf[8];
#pragma unroll
    for (int i = 0; i < 2; ++i)
      af[i] = *(const shortx8*)(As + (wr * 32 + i * 16 + l16) * 32 + quad * 8);
#pragma unroll
    for (int j = 0; j < 8; ++j)
      bf[j] = *(const shortx8*)(Bs + (wc * 128 + j * 16 + l16) * 32 + quad * 8);
#pragma unroll
    for (int i = 0; i < 2; ++i)
#pragma unroll
      for (int j = 0; j < 8; ++j)
        acc[i][j] = MFMA_BF16(af[i], bf[j], acc[i][j], 0, 0, 0);
  }

  // ---- epilogue: residual add + per-row LN over 512 cols ----
  float e[2][8][4];
  float sP[2][4] = {{0.f, 0.f, 0.f, 0.f}, {0.f, 0.f, 0.f, 0.f}};
  float qP[2][4] = {{0.f, 0.f, 0.f, 0.f}, {0.f, 0.f, 0.f, 0.f}};
#pragma unroll
  for (int i = 0; i < 2; ++i)
#pragma unroll
    for (int r = 0; r < 4; ++r) {
      int rloc = wr * 32 + i * 16 + quad * 4 + r;
      long rbase = (row0 + rloc) * DMODEL;
#pragma unroll
      for (int j = 0; j < 8; ++j) {
        int col = wc * 128 + j * 16 + l16;
        float v = acc[i][j][r] + bias[col] + x_f[rbase + col];
        e[i][j][r] = v;
        sP[i][r] += v;
        qP[i][r] += v * v;
      }
    }
  // reduce across the 16 l16-lanes (partners share quad -> same rows)
#pragma unroll
  for (int m = 1; m < 16; m <<= 1)
#pragma unroll
    for (int i = 0; i < 2; ++i)
#pragma unroll
      for (int r = 0; r < 4; ++r) {
        sP[i][r] += __shfl_xor(sP[i][r], m, 64);
        qP[i][r] += __shfl_xor(qP[i][r], m, 64);
      }
  if (l16 == 0) {
#pragma unroll
    for (int i = 0; i < 2; ++i)
#pragma unroll
      for (int r = 0; r < 4; ++r) {
        int rloc = wr * 32 + i * 16 + quad * 4 + r;
        redS[rloc][wc] = sP[i][r];
        redQ[rloc][wc] = qP[i][r];
      }
  }
  __syncthreads();
  if (tid < 64) {
    float S = redS[tid][0] + redS[tid][1] + redS[tid][2] + redS[tid][3];
    float Q = redQ[tid][0] + redQ[tid][1] + redQ[tid][2] + redQ[tid][3];
    float mean = S * (1.0f / 512.0f);
    float var = Q * (1.0f / 512.0f) - mean * mean;
    meanr[tid] = mean;
    rstdr[tid] = rsqrtf(var + 1e-5f);
  }
  __syncthreads();
#pragma unroll
  for (int i = 0; i < 2; ++i)
#pragma unroll
    for (int r = 0; r < 4; ++r) {
      int rloc = wr * 32 + i * 16 + quad * 4 + r;
      long rbase = (row0 + rloc) * DMODEL;
      float mean = meanr[rloc], rstd = rstdr[rloc];
#pragma unroll
      for (int j = 0; j < 8; ++j) {
        int col = wc * 128 + j * 16 + l16;
        float o = (e[i][j][r] - mean) * rstd * gamma[col] + beta[col];
        x_f[rbase + col] = o;
        x_b[rbase + col] = f2bf(o);
      }
    }
}

// ---------------- 256x256 8-wave 4-phase bf16 GEMM + T2 + XCD swizzle ------
__device__ __forceinline__ void frag_read(const unsigned short* __restrict__ base,
                                          int R, int quad, shortx8& f0, shortx8& f1) {
  int pc = quad ^ (R & 7);
  const unsigned short* p = base + R * 64;
  f0 = *(const shortx8*)(p + pc * 8);          // true chunk = quad
  f1 = *(const shortx8*)(p + (pc ^ 4) * 8);    // true chunk = quad+4
}

__global__ __launch_bounds__(512, 2) void gemm256_kernel(
    const unsigned short* __restrict__ A,   // [M,K] bf16 row-major
    const unsigned short* __restrict__ B,   // [Npad,K] bf16 row-major
    const float* __restrict__ bias,         // [Nreal] or nullptr
    float* __restrict__ Cf,                 // [M,ldC] f32 or nullptr
    unsigned short* __restrict__ Cb,        // [M,ldC] bf16 or nullptr
    int K, int Nreal, int ldC, int relu) {
  __shared__ unsigned short As[2][256 * 64];
  __shared__ unsigned short Bs[2][256 * 64];
  const int tid = threadIdx.x;
  const int lane = tid & 63;
  const int wave = tid >> 6;       // 0..7
  const int wm = wave >> 2;        // 0..1 : row half (128 rows)
  const int wn = wave & 3;         // 0..3 : col quarter (64 cols)
  const int l16 = lane & 15;
  const int quad = lane >> 4;
  // XCD-aware bijective swizzle (nwg % 8 == 0 for all our grids)
  const int nwgx = gridDim.x;
  const int flat = blockIdx.y * nwgx + blockIdx.x;
  const int cpx = (nwgx * gridDim.y) >> 3;
  const int swz = (flat & 7) * cpx + (flat >> 3);
  const long rowA0 = (long)(swz % nwgx) * 256;
  const long rowB0 = (long)(swz / nwgx) * 256;

  floatx4 acc[8][4] = {};

  // staging: linear LDS dest; global source column inverse-swizzled (T2)
  const int srow = tid >> 3;
  const int scol = (((tid & 7) ^ ((tid >> 3) & 7)) << 3);
  const unsigned short* gA = A + (rowA0 + srow) * (long)K + scol;
  const unsigned short* gB = B + (rowB0 + srow) * (long)K + scol;
  const int loff = tid * 8;
  const long rstep = 64 * (long)K;    // (R+64)&7 == R&7 so swizzle holds

  // prologue: K-tile 0 into buffer 0
#pragma unroll
  for (int is = 0; is < 4; ++is) {
    GLOAD_LDS(gA + is * rstep, &As[0][is * 4096 + loff]);
    GLOAD_LDS(gB + is * rstep, &Bs[0][is * 4096 + loff]);
  }
  asm volatile("s_waitcnt vmcnt(0)" ::: "memory");
  phase_barrier();

  const int KT = K >> 6;
  for (int kt = 0; kt < KT; ++kt) {
    const int cur = kt & 1;
    const unsigned short* Ab = As[cur];
    const unsigned short* Bb = Bs[cur];
    unsigned short* An = As[cur ^ 1];
    unsigned short* Bn = Bs[cur ^ 1];
    const bool stage = (kt + 1) < KT;
    const unsigned short* gAn = gA + (long)(kt + 1) * 64;
    const unsigned short* gBn = gB + (long)(kt + 1) * 64;

    shortx8 af[4][2], bf[4][2];

    // ---- phase 0: read af(m0-3)+bf(n0-1); stage ALL next-A ----
#pragma unroll
    for (int m = 0; m < 4; ++m)
      frag_read(Ab, wm * 128 + m * 16 + l16, quad, af[m][0], af[m][1]);
#pragma unroll
    for (int n = 0; n < 2; ++n)
      frag_read(Bb, wn * 64 + n * 16 + l16, quad, bf[n][0], bf[n][1]);
    if (stage) {
      GLOAD_LDS(gAn, An + loff);
      GLOAD_LDS(gAn + rstep, An + 4096 + loff);
      GLOAD_LDS(gAn + 2 * rstep, An + 8192 + loff);
      GLOAD_LDS(gAn + 3 * rstep, An + 12288 + loff);
    }
    phase_barrier();
    __builtin_amdgcn_s_setprio(1);
#pragma unroll
    for (int m = 0; m < 4; ++m)
#pragma unroll
      for (int n = 0; n < 2; ++n) {
        acc[m][n] = MFMA_BF16(af[m][0], bf[n][0], acc[m][n], 0, 0, 0);
        acc[m][n] = MFMA_BF16(af[m][1], bf[n][1], acc[m][n], 0, 0, 0);
      }
    __builtin_amdgcn_s_setprio(0);
    phase_barrier();

    // ---- phase 1: read bf(n2-3); stage ALL next-B ----
#pragma unroll
    for (int n = 2; n < 4; ++n)
      frag_read(Bb, wn * 64 + n * 16 + l16, quad, bf[n][0], bf[n][1]);
    if (stage) {
      GLOAD_LDS(gBn, Bn + loff);
      GLOAD_LDS(gBn + rstep, Bn + 4096 + loff);
      GLOAD_LDS(gBn + 2 * rstep, Bn + 8192 + loff);
      GLOAD_LDS(gBn + 3 * rstep, Bn + 12288 + loff);
    }
    phase_barrier();
    __builtin_amdgcn_s_setprio(1);
#pragma unroll
    for (int m = 0; m < 4; ++m)
#pragma unroll
      for (int n = 2; n < 4; ++n) {
        acc[m][n] = MFMA_BF16(af[m][0], bf[n][0], acc[m][n], 0, 0, 0);
        acc[m][n] = MFMA_BF16(af[m][1], bf[n][1], acc[m][n], 0, 0, 0);
      }
    __builtin_amdgcn_s_setprio(0);
    phase_barrier();

    // ---- phase 2: read af(m4-7); MFMA m4-7 x n0-1 ----
#pragma unroll
    for (int m = 0; m < 4; ++m)
      frag_read(Ab, wm * 128 + 64 + m * 16 + l16, quad, af[m][0], af[m][1]);
    phase_barrier();
    __builtin_amdgcn_s_setprio(1);
#pragma unroll
    for (int m = 0; m < 4; ++m)
#pragma unroll
      for (int n = 0; n < 2; ++n) {
        acc[4 + m][n] = MFMA_BF16(af[m][0], bf[n][0], acc[4 + m][n], 0, 0, 0);
        acc[4 + m][n] = MFMA_BF16(af[m][1], bf[n][1], acc[4 + m][n], 0, 0, 0);
      }
    __builtin_amdgcn_s_setprio(0);
    phase_barrier();

    // ---- phase 3: MFMA m4-7 x n2-3; tile-end drain ----
    __builtin_amdgcn_s_setprio(1);
#pragma unroll
    for (int m = 0; m < 4; ++m)
#pragma unroll
      for (int n = 2; n < 4; ++n) {
        acc[4 + m][n] = MFMA_BF16(af[m][0], bf[n][0], acc[4 + m][n], 0, 0, 0);
        acc[4 + m][n] = MFMA_BF16(af[m][1], bf[n][1], acc[4 + m][n], 0, 0, 0);
      }
    __builtin_amdgcn_s_setprio(0);
    asm volatile("s_waitcnt vmcnt(0)" ::: "memory");
    phase_barrier();
  }

  // epilogue (registers only)
#pragma unroll
  for (int m = 0; m < 8; ++m) {
    int row = (int)rowA0 + wm * 128 + m * 16 + quad * 4;
#pragma unroll
    for (int n = 0; n < 4; ++n) {
      int col = (int)rowB0 + wn * 64 + n * 16 + l16;
      if (col < Nreal) {
        float bv = bias ? bias[col] : 0.0f;
#pragma unroll
        for (int r = 0; r < 4; ++r) {
          float v = acc[m][n][r] + bv;
          if (relu) v = fmaxf(v, 0.0f);
          long off = (long)(row + r) * ldC + col;
          if (Cf) Cf[off] = v;
          if (Cb) Cb[off] = f2bf(v);
        }
      }
    }
  }
}

// ---------------- attention: one block per (b,h), parity-split j-loop ------
__global__ __launch_bounds__(256) void attn_kernel(
    const float* __restrict__ qkv,          // [ROWS, 1536]
    unsigned short* __restrict__ o_b) {     // [ROWS, 512] bf16
  __shared__ float Ks[SEQ * DHEAD];
  __shared__ float Vs[SEQ * DHEAD];
  __shared__ float Ds[SEQ];
  int b = blockIdx.x >> 3, h = blockIdx.x & 7;
  const float* base = qkv + (long)b * SEQ * 1536;
  int hoff = h * DHEAD;
  for (int idx4 = threadIdx.x; idx4 < SEQ * DHEAD / 4; idx4 += 256) {
    int l = idx4 >> 4;               // 16 float4 per 64-float row
    int c4 = (idx4 & 15) << 2;
    *(float4*)(Ks + l * 64 + c4) = *(const float4*)(base + l * 1536 + 512 + hoff + c4);
    *(float4*)(Vs + l * 64 + c4) = *(const float4*)(base + l * 1536 + 1024 + hoff + c4);
  }
  __syncthreads();
  int l = threadIdx.x & 127;
  int half = threadIdx.x >> 7;
  float q[DHEAD];
#pragma unroll
  for (int c4 = 0; c4 < 16; ++c4)
    *(float4*)(q + c4 * 4) = *(const float4*)(base + l * 1536 + hoff + c4 * 4);
  float o[DHEAD];
#pragma unroll
  for (int c = 0; c < DHEAD; ++c) o[c] = 0.f;
  float denom = 0.f;
  for (int j = half; j <= l; j += 2) {  // causal; parity split balances halves
    const float* kr = Ks + j * DHEAD;
    float s0 = 0.f, s1 = 0.f, s2 = 0.f, s3 = 0.f;
#pragma unroll
    for (int c = 0; c < DHEAD; c += 4) {
      s0 += q[c] * kr[c];         s1 += q[c + 1] * kr[c + 1];
      s2 += q[c + 2] * kr[c + 2]; s3 += q[c + 3] * kr[c + 3];
    }
    float p = __expf(((s0 + s1) + (s2 + s3)) * 0.125f);  // scale = 1/sqrt(64)
    denom += p;
    const float* vr = Vs + j * DHEAD;
#pragma unroll
    for (int c = 0; c < DHEAD; ++c) o[c] += p * vr[c];
  }
  __syncthreads();            // K no longer needed; reuse Ks for partials
  if (half) {
    float* os = Ks + l * DHEAD;
#pragma unroll
    for (int c = 0; c < DHEAD; ++c) os[c] = o[c];
    Ds[l] = denom;
  }
  __syncthreads();
  if (!half) {
    float dtot = denom + Ds[l];
    float inv = 1.0f / dtot;
    const float* os = Ks + l * DHEAD;
    unsigned short* dst = o_b + ((long)b * SEQ + l) * DMODEL + hoff;
#pragma unroll
    for (int c0 = 0; c0 < DHEAD; c0 += 8) {
      shortx8 ov;
#pragma unroll
      for (int k = 0; k < 8; ++k)
        ov[k] = (short)f2bf((o[c0 + k] + os[c0 + k]) * inv);
      *(shortx8*)(dst + c0) = ov;
    }
  }
}

extern "C" void kernel_launch(void* const* d_in, const int* in_sizes, int n_in,
                              void* d_out, int out_size, void* d_ws, size_t ws_size,
                              hipStream_t stream) {
  const int* item_ids = (const int*)d_in[0];
  const int* seg_ids = (const int*)d_in[1];
  // d_in[2] pad_mask: all-false; d_in[3] future_mask: causal; d_in[4] max_len.
  const float* emb  = (const float*)d_in[5];
  const float* Wqkv = (const float*)d_in[6];
  const float* bqkv = (const float*)d_in[7];
  const float* Wo   = (const float*)d_in[8];
  const float* bo   = (const float*)d_in[9];
  const float* W1   = (const float*)d_in[10];
  const float* b1   = (const float*)d_in[11];
  const float* W2   = (const float*)d_in[12];
  const float* b2   = (const float*)d_in[13];
  const float* ln1s = (const float*)d_in[14];
  const float* ln1b = (const float*)d_in[15];
  const float* ln2s = (const float*)d_in[16];
  const float* ln2b = (const float*)d_in[17];
  const float* Wout = (const float*)d_in[18];
  const float* bout = (const float*)d_in[19];
  float* out = (float*)d_out;

  char* ws = (char*)d_ws;
  size_t off = 0;
  auto alloc = [&](size_t bytes) {
    void* p = ws + off;
    off += (bytes + 255) & ~(size_t)255;
    return p;
  };
  float* x_f  = (float*)alloc((size_t)ROWS * 512 * 4);
  unsigned short* x_b = (unsigned short*)alloc((size_t)ROWS * 512 * 2);
  float* qkv_f = (float*)alloc((size_t)ROWS * 1536 * 4);
  unsigned short* o_b = (unsigned short*)alloc((size_t)ROWS * 512 * 2);
  unsigned short* h_b = (unsigned short*)alloc((size_t)ROWS * 1024 * 2);
  unsigned short* wqkv_b = (unsigned short*)alloc((size_t)2 * 1536 * 512 * 2);
  unsigned short* wo_b = (unsigned short*)alloc((size_t)2 * 512 * 512 * 2);
  unsigned short* w1_b = (unsigned short*)alloc((size_t)2 * 1024 * 512 * 2);
  unsigned short* w2_b = (unsigned short*)alloc((size_t)2 * 512 * 1024 * 2);
  unsigned short* wout_b = (unsigned short*)alloc((size_t)NOUT_PAD * 512 * 2);
  int* starts = (int*)alloc((size_t)(ROWS + 1) * 4);

  prep_kernel<<<2048, 256, 0, stream>>>(
      Wqkv, Wo, W1, W2, Wout, wqkv_b, wo_b, w1_b, w2_b, wout_b, seg_ids, starts);

  seg_mean_kernel<<<ROWS, 128, 0, stream>>>(item_ids, starts, emb, x_f, x_b);

  for (int i = 0; i < 2; ++i) {
    // qkv = x @ Wqkv[i]^T + bqkv[i]   [8192,1536] f32
    gemm256_kernel<<<dim3(32, 6), 512, 0, stream>>>(
        x_b, wqkv_b + (long)i * 1536 * 512, bqkv + i * 1536,
        qkv_f, nullptr, 512, 1536, 1536, 0);
    attn_kernel<<<512, 256, 0, stream>>>(qkv_f, o_b);
    // x = LN1(x + o @ Wo[i]^T + bo[i])   (fused GEMM+LN)
    gemm_ln_kernel<<<128, 512, 0, stream>>>(
        o_b, wo_b + (long)i * 512 * 512, bo + i * 512,
        ln1s + i * 512, ln1b + i * 512, x_f, x_b, 512);
    // h = relu(x @ W1[i]^T + b1[i])  bf16 only
    gemm_bt_kernel<<<dim3(64, 8), 256, 0, stream>>>(
        x_b, w1_b + (long)i * 1024 * 512, b1 + i * 1024,
        nullptr, h_b, 512, 1024, 1024, 1);
    // x = LN2(x + h @ W2[i]^T + b2[i])   (fused GEMM+LN)
    gemm_ln_kernel<<<128, 512, 0, stream>>>(
        h_b, w2_b + (long)i * 512 * 1024, b2 + i * 512,
        ln2s + i * 512, ln2b + i * 512, x_f, x_b, 1024);
  }

  // out = x @ Wout^T + bout   [8192, 10000] f32
  gemm256_kernel<<<dim3(32, 40), 512, 0, stream>>>(
      x_b, wout_b, bout, out, nullptr, 512, NTYPES, NTYPES, 0);
}